// Round 11
// baseline (302.149 us; speedup 1.0000x reference)
//
#include <hip/hip_runtime.h>
#include <cfloat>
#include <cmath>

#define DEVINL __device__ __forceinline__

constexpr int N_ = 4, C_ = 21, H_ = 512, W_ = 512;
constexpr int P_ = 171;           // pooled H/W
constexpr int Q_ = 169;           // point grid: P-3+1
constexpr int NC_ = N_ * C_;      // 84
constexpr int HW_ = H_ * W_;      // 262144 = 2^18
constexpr int PP_ = 29241;        // P_*P_ (pack layout, unpadded)
constexpr int PROW_ = 176;        // padded row stride for pr/la (16B-aligned; cols 171..175 = 0)
constexpr int PPAD_ = PROW_ * P_; // 30096 per (n,c) image
constexpr int NCOV_ = 189;        // 9 + 9 + 45 + 45 + 81
constexpr float EPS_ = 5e-4f;
constexpr int RC_ = 13;           // point-rows per k_cov chunk (13 x 13 = 169 exact)
constexpr int NCH_ = 13;          // chunks
constexpr int G_ = 43;            // col-quads per row (covers x0=0..168)

DEVINL constexpr int tstart(int d) { return d * 9 - d * (d - 1) / 2; }

DEVINL float wave_sum(float v) {
#pragma unroll
    for (int o = 32; o > 0; o >>= 1) v += __shfl_down(v, o, 64);
    return v;
}

// ---------------------------------------------------------------------------
// k_bits: thread per pooled cell (n,i,j). UNCHANGED.
// ---------------------------------------------------------------------------
__global__ __launch_bounds__(256) void k_bits(const int* __restrict__ target,
                                              unsigned* __restrict__ pack) {
    int tid = blockIdx.x * 256 + threadIdx.x;
    if (tid >= N_ * PP_) return;
    int cell = tid % PP_;
    int n = tid / PP_;
    int j = cell % P_;
    int i = cell / P_;
    int hl = 3 * i - 1; if (hl < 0) hl = 0;
    int wl = 3 * j - 1; if (wl < 0) wl = 0;
    int hmax = 3 * i + 1, wmax = 3 * j + 1;
    const int* tb = target + (size_t)n * HW_;
    unsigned oh = 0, px = 0;
#pragma unroll
    for (int r = 0; r < 3; ++r) {
        int hh = hl + r;
        bool hv = hh <= hmax;
        const int* trow = tb + hh * W_;
#pragma unroll
        for (int dc = 0; dc < 3; ++dc) {
            int ww = wl + dc;
            int t = trow[ww];
            if (hv && (ww <= wmax) && t >= 0 && t < C_) {
                oh |= 1u << t;
                px |= 1u << (r * 3 + dc);
            }
        }
    }
    pack[tid] = oh | (px << 23);
}

// ---------------------------------------------------------------------------
// k_ce v2: thread per 4 pixels, 21 float4 loads live in registers. UNCHANGED.
// ---------------------------------------------------------------------------
__global__ __launch_bounds__(256) void k_ce(const float* __restrict__ score,
                                            const int* __restrict__ target,
                                            float* __restrict__ cov_ce) {
    int tid = blockIdx.x * 256 + threadIdx.x;
    int p0 = tid * 4;
    int n = p0 >> 18;
    int hw = p0 & (HW_ - 1);
    const float* sp = score + (size_t)n * C_ * HW_ + hw;

    float4 s[C_];
#pragma unroll
    for (int c = 0; c < C_; ++c)
        s[c] = *(const float4*)(sp + (size_t)c * HW_);
    int4 t4 = *(const int4*)(target + p0);

    float4 se = {0.f, 0.f, 0.f, 0.f};
    float4 stgt = {0.f, 0.f, 0.f, 0.f};
#pragma unroll
    for (int c = 0; c < C_; ++c) {
        se.x += __expf(s[c].x);
        se.y += __expf(s[c].y);
        se.z += __expf(s[c].z);
        se.w += __expf(s[c].w);
        if (t4.x == c) stgt.x = s[c].x;
        if (t4.y == c) stgt.y = s[c].y;
        if (t4.z == c) stgt.z = s[c].z;
        if (t4.w == c) stgt.w = s[c].w;
    }
    float nll = 0.f, cnt = 0.f;
    if (t4.x != 255) { nll += __logf(se.x) - stgt.x; cnt += 1.f; }
    if (t4.y != 255) { nll += __logf(se.y) - stgt.y; cnt += 1.f; }
    if (t4.z != 255) { nll += __logf(se.z) - stgt.z; cnt += 1.f; }
    if (t4.w != 255) { nll += __logf(se.w) - stgt.w; cnt += 1.f; }

    nll = wave_sum(nll);
    cnt = wave_sum(cnt);
    __shared__ float rn[4], rc[4];
    int wv = threadIdx.x >> 6, lane = threadIdx.x & 63;
    if (lane == 0) { rn[wv] = nll; rc[wv] = cnt; }
    __syncthreads();
    if (threadIdx.x == 0) {
        atomicAdd(&cov_ce[NC_ * NCOV_ + 0], rn[0] + rn[1] + rn[2] + rn[3]);
        atomicAdd(&cov_ce[NC_ * NCOV_ + 1], rc[0] + rc[1] + rc[2] + rc[3]);
    }
}

// ---------------------------------------------------------------------------
// k_pool v3: thread per (n,c,i,g). Same as v2 plus: PROW_=176 and the last
// quad (g=42) zero-fills pad columns 171..175 so branch-free k_cov reads of
// the pad are exact zeros (harness poisons ws with 0xAA).
// ---------------------------------------------------------------------------
template <int IDX>
DEVINL void do_cell(const float (&f)[3][16], unsigned pk, int c, float* prp, float* lap) {
    unsigned px = pk >> 23;
    float vm = -FLT_MAX;
#pragma unroll
    for (int r = 0; r < 3; ++r)
#pragma unroll
        for (int dc = 0; dc < 3; ++dc)
            vm = fmaxf(vm, ((px >> (r * 3 + dc)) & 1u) ? f[r][IDX + dc] : -FLT_MAX);
    float p = __builtin_amdgcn_rcpf(1.f + __expf(-vm));
    p = fminf(fmaxf(p, 1e-6f), 1.f);
    *prp = p;
    *lap = ((pk >> c) & 1u) ? 1.f : 0.f;
}

__global__ __launch_bounds__(256) void k_pool(const float* __restrict__ score,
                                              const unsigned* __restrict__ pack,
                                              float* __restrict__ pr,
                                              float* __restrict__ la) {
    int tid = blockIdx.x * 256 + threadIdx.x;
    if (tid >= NC_ * P_ * G_) return;
    int g = tid % G_;
    int rest = tid / G_;
    int i = rest % P_;
    int ncidx = rest / P_;
    int n = ncidx / C_;
    int c = ncidx - n * C_;

    int hl = 3 * i - 1; if (hl < 0) hl = 0;
    int b = (g == 0) ? 0 : 12 * g - 4;
    int o3 = (b + 15 < W_) ? 12 : 8;

    const float* sb = score + (size_t)ncidx * HW_ + (size_t)hl * W_ + b;
    float f[3][16];
#pragma unroll
    for (int r = 0; r < 3; ++r) {
        const float* rp = sb + r * W_;
        float4 q0 = *(const float4*)(rp);
        float4 q1 = *(const float4*)(rp + 4);
        float4 q2 = *(const float4*)(rp + 8);
        float4 q3 = *(const float4*)(rp + o3);
        f[r][0] = q0.x;  f[r][1] = q0.y;  f[r][2] = q0.z;  f[r][3] = q0.w;
        f[r][4] = q1.x;  f[r][5] = q1.y;  f[r][6] = q1.z;  f[r][7] = q1.w;
        f[r][8] = q2.x;  f[r][9] = q2.y;  f[r][10] = q2.z; f[r][11] = q2.w;
        f[r][12] = q3.x; f[r][13] = q3.y; f[r][14] = q3.z; f[r][15] = q3.w;
    }

    const unsigned* pkp = pack + n * PP_ + i * P_ + 4 * g;
    size_t ob = (size_t)ncidx * PPAD_ + (size_t)i * PROW_ + 4 * g;
    if (g == 0) {
        do_cell<0>(f, pkp[0], c, pr + ob + 0, la + ob + 0);
        do_cell<2>(f, pkp[1], c, pr + ob + 1, la + ob + 1);
        do_cell<5>(f, pkp[2], c, pr + ob + 2, la + ob + 2);
        do_cell<8>(f, pkp[3], c, pr + ob + 3, la + ob + 3);
    } else {
        do_cell<3>(f, pkp[0], c, pr + ob + 0, la + ob + 0);
        do_cell<6>(f, pkp[1], c, pr + ob + 1, la + ob + 1);
        do_cell<9>(f, pkp[2], c, pr + ob + 2, la + ob + 2);
        if (g < G_ - 1)
            do_cell<12>(f, pkp[3], c, pr + ob + 3, la + ob + 3);
        else {
            // g=42: 4g=168 -> ob+3 is col 171; zero cols 171..175
#pragma unroll
            for (int z = 3; z < 8; ++z) { pr[ob + z] = 0.f; la[ob + z] = 0.f; }
        }
    }
}

// ---------------------------------------------------------------------------
// k_cov v7 (anti-spill): three plain kernels, branch-free inner loops.
// R8-R10 evidence: WRITE_SIZE 0.45-6.4 GB = accumulator arrays spilled to
// scratch in every prior variant (conditional acc updates + low VGPR caps).
// Fixes: (a) no 'if' around accumulator updates — tail points masked by
// multiplying LEFT factors with mp in {0,1}; pad cols are zero so all reads
// are harmless; (b) no templates/switch — straight code per kernel;
// (c) __launch_bounds__(256,1): allocator cap ~512 VGPR, spill never forced.
// Data read directly from global (21 MB, L2/L3-hot after k_pool).
// ---------------------------------------------------------------------------
__global__ __launch_bounds__(256, 1) void k_cov_tri(const float* __restrict__ xg,
                                                    float* __restrict__ cov,
                                                    int s1base, int s2base) {
    int nc = blockIdx.x;
    int r0 = blockIdx.y * RC_;
    const float* X = xg + (size_t)nc * PPAD_ + (size_t)r0 * PROW_;

    float s1[9], s2[45];
#pragma unroll
    for (int k = 0; k < 9; ++k) s1[k] = 0.f;
#pragma unroll
    for (int k = 0; k < 45; ++k) s2[k] = 0.f;

    for (int qi = threadIdx.x; qi < RC_ * G_; qi += 256) {  // 559 quads
        int lr = qi / G_;
        int q = qi - lr * G_;
        int x0 = 4 * q;
        const float* base = X + lr * PROW_ + x0;
        float v[3][8];
#pragma unroll
        for (int r = 0; r < 3; ++r) {
            float4 u0 = *(const float4*)(base + r * PROW_);
            float4 u1 = *(const float4*)(base + r * PROW_ + 4);
            v[r][0] = u0.x; v[r][1] = u0.y; v[r][2] = u0.z; v[r][3] = u0.w;
            v[r][4] = u1.x; v[r][5] = u1.y; v[r][6] = u1.z; v[r][7] = u1.w;
        }
#pragma unroll
        for (int p = 0; p < 4; ++p) {
            float mp = (x0 + p < Q_) ? 1.f : 0.f;   // select, not branch
            float w[9];
#pragma unroll
            for (int d = 0; d < 9; ++d) w[d] = v[d / 3][p + d % 3] * mp;
#pragma unroll
            for (int d = 0; d < 9; ++d) s1[d] += w[d];
            int k = 0;
#pragma unroll
            for (int d = 0; d < 9; ++d)
#pragma unroll
                for (int e = d; e < 9; ++e) {
                    s2[k] += w[d] * v[e / 3][p + e % 3];
                    ++k;
                }
        }
    }

    __shared__ float red[4][54];
    int lane = threadIdx.x & 63, wv = threadIdx.x >> 6;
#pragma unroll
    for (int k = 0; k < 9; ++k) { float v2 = wave_sum(s1[k]); if (lane == 0) red[wv][k] = v2; }
#pragma unroll
    for (int k = 0; k < 45; ++k) { float v2 = wave_sum(s2[k]); if (lane == 0) red[wv][9 + k] = v2; }
    __syncthreads();
    for (int k = threadIdx.x; k < 54; k += 256) {
        float v2 = red[0][k] + red[1][k] + red[2][k] + red[3][k];
        int dst = (k < 9) ? (s1base + k) : (s2base + k - 9);
        atomicAdd(&cov[nc * NCOV_ + dst], v2);
    }
}

__global__ __launch_bounds__(256, 1) void k_cov_ab(const float* __restrict__ la,
                                                   const float* __restrict__ pr,
                                                   float* __restrict__ cov) {
    int nc = blockIdx.x;
    int r0 = blockIdx.y * RC_;
    int RA = blockIdx.z;                         // A-row offset 0..2
    const float* A = la + (size_t)nc * PPAD_ + (size_t)r0 * PROW_;
    const float* B = pr + (size_t)nc * PPAD_ + (size_t)r0 * PROW_;

    float acc[27];
#pragma unroll
    for (int k = 0; k < 27; ++k) acc[k] = 0.f;

    for (int qi = threadIdx.x; qi < RC_ * G_; qi += 256) {
        int lr = qi / G_;
        int q = qi - lr * G_;
        int x0 = 4 * q;
        const float* ap = A + (lr + RA) * PROW_ + x0;
        const float* bp = B + lr * PROW_ + x0;
        float a[8], b[3][8];
        {
            float4 u0 = *(const float4*)(ap);
            float4 u1 = *(const float4*)(ap + 4);
            a[0] = u0.x; a[1] = u0.y; a[2] = u0.z; a[3] = u0.w;
            a[4] = u1.x; a[5] = u1.y; a[6] = u1.z; a[7] = u1.w;
        }
#pragma unroll
        for (int r = 0; r < 3; ++r) {
            float4 u0 = *(const float4*)(bp + r * PROW_);
            float4 u1 = *(const float4*)(bp + r * PROW_ + 4);
            b[r][0] = u0.x; b[r][1] = u0.y; b[r][2] = u0.z; b[r][3] = u0.w;
            b[r][4] = u1.x; b[r][5] = u1.y; b[r][6] = u1.z; b[r][7] = u1.w;
        }
#pragma unroll
        for (int p = 0; p < 4; ++p) {
            float mp = (x0 + p < Q_) ? 1.f : 0.f;
            float am[3];
#pragma unroll
            for (int c1 = 0; c1 < 3; ++c1) am[c1] = a[p + c1] * mp;
#pragma unroll
            for (int c1 = 0; c1 < 3; ++c1)
#pragma unroll
                for (int e = 0; e < 9; ++e)
                    acc[c1 * 9 + e] += am[c1] * b[e / 3][p + e % 3];
        }
    }

    __shared__ float red[4][27];
    int lane = threadIdx.x & 63, wv = threadIdx.x >> 6;
#pragma unroll
    for (int k = 0; k < 27; ++k) { float v2 = wave_sum(acc[k]); if (lane == 0) red[wv][k] = v2; }
    __syncthreads();
    for (int k = threadIdx.x; k < 27; k += 256) {
        float v2 = red[0][k] + red[1][k] + red[2][k] + red[3][k];
        atomicAdd(&cov[nc * NCOV_ + 108 + RA * 27 + k], v2);
    }
}

// ---------------------------------------------------------------------------
// k_final: per-(n,c) 9x9 algebra. UNCHANGED.
// ---------------------------------------------------------------------------
__global__ __launch_bounds__(128) void k_final(const float* __restrict__ cov,
                                               float* __restrict__ out) {
    __shared__ float red[128];
    int t = threadIdx.x;
    float my = 0.f;
    if (t < NC_) {
        const float* S = cov + t * NCOV_;
        const float Lf = (float)(Q_ * Q_);  // 28561
        float sA[9], sB[9];
#pragma unroll
        for (int d = 0; d < 9; ++d) { sA[d] = S[d]; sB[d] = S[9 + d]; }
        float laC[45], M[45], Cm[81];
        {
            int k = 0;
#pragma unroll
            for (int d = 0; d < 9; ++d)
#pragma unroll
                for (int e = d; e < 9; ++e) {
                    laC[k] = S[18 + k] - sA[d] * sA[e] / Lf;
                    M[k] = S[63 + k] - sB[d] * sB[e] / Lf + (d == e ? EPS_ : 0.f);
                    ++k;
                }
#pragma unroll
            for (int d = 0; d < 9; ++d)
#pragma unroll
                for (int e = 0; e < 9; ++e)
                    Cm[d * 9 + e] = S[108 + d * 9 + e] - sA[d] * sB[e] / Lf;
        }
#pragma unroll
        for (int j = 0; j < 9; ++j) {
            float s = M[tstart(j)];
#pragma unroll
            for (int k = 0; k < j; ++k) { float l = M[tstart(k) + (j - k)]; s -= l * l; }
            float dj = sqrtf(fmaxf(s, 1e-30f));
            M[tstart(j)] = dj;
            float inv = 1.f / dj;
#pragma unroll
            for (int i = j + 1; i < 9; ++i) {
                float s2 = M[tstart(j) + (i - j)];
#pragma unroll
                for (int k = 0; k < j; ++k)
                    s2 -= M[tstart(k) + (i - k)] * M[tstart(k) + (j - k)];
                M[tstart(j) + (i - j)] = s2 * inv;
            }
        }
#pragma unroll
        for (int p = 0; p < 9; ++p) {
#pragma unroll
            for (int i = 0; i < 9; ++i) {
                float s = Cm[p * 9 + i];
#pragma unroll
                for (int k = 0; k < i; ++k)
                    s -= M[tstart(k) + (i - k)] * Cm[p * 9 + k];
                Cm[p * 9 + i] = s / M[tstart(i)];
            }
        }
#pragma unroll
        for (int d = 0; d < 9; ++d)
#pragma unroll
            for (int e = d; e < 9; ++e) {
                float s = 0.f;
#pragma unroll
                for (int i = 0; i < 9; ++i) s += Cm[d * 9 + i] * Cm[e * 9 + i];
                laC[tstart(d) + (e - d)] -= s;
                if (d == e) laC[tstart(d)] += EPS_;
            }
        float rmi = 0.f;
#pragma unroll
        for (int j = 0; j < 9; ++j) {
            float s = laC[tstart(j)];
#pragma unroll
            for (int k = 0; k < j; ++k) { float l = laC[tstart(k) + (j - k)]; s -= l * l; }
            float dj = sqrtf(fmaxf(s, 0.f));
            laC[tstart(j)] = dj;
            float inv = 1.f / fmaxf(dj, 1e-30f);
#pragma unroll
            for (int i = j + 1; i < 9; ++i) {
                float s2 = laC[tstart(j) + (i - j)];
#pragma unroll
                for (int k = 0; k < j; ++k)
                    s2 -= laC[tstart(k) + (i - k)] * laC[tstart(k) + (j - k)];
                laC[tstart(j) + (i - j)] = s2 * inv;
            }
            rmi += __logf(dj + 1e-8f);
        }
        my = rmi;
    }
    red[t] = my;
    __syncthreads();
#pragma unroll
    for (int o = 64; o > 0; o >>= 1) {
        if (t < o) red[t] += red[t + o];
        __syncthreads();
    }
    if (t == 0) {
        float rmi_total = red[0] / 36.f;  // / (N * HALF_D)
        float ce = cov[NC_ * NCOV_ + 0] / cov[NC_ * NCOV_ + 1];
        out[0] = 0.5f * ce + 0.5f * rmi_total;
    }
}

extern "C" void kernel_launch(void* const* d_in, const int* in_sizes, int n_in,
                              void* d_out, int out_size, void* d_ws, size_t ws_size,
                              hipStream_t stream) {
    const float* score = (const float*)d_in[0];
    const int* target = (const int*)d_in[1];
    float* pr = (float*)d_ws;
    float* la = pr + (size_t)NC_ * PPAD_;
    float* cov = la + (size_t)NC_ * PPAD_;              // NC_*NCOV_ + 2 floats
    unsigned* pack = (unsigned*)(cov + NC_ * NCOV_ + 2);
    hipMemsetAsync(cov, 0, (size_t)(NC_ * NCOV_ + 2) * sizeof(float), stream);

    k_bits<<<dim3((N_ * PP_ + 255) / 256), dim3(256), 0, stream>>>(target, pack);
    k_ce<<<dim3(N_ * HW_ / 4 / 256), dim3(256), 0, stream>>>(score, target, cov);
    k_pool<<<dim3((NC_ * P_ * G_ + 255) / 256), dim3(256), 0, stream>>>(score, pack, pr, la);
    k_cov_tri<<<dim3(NC_, NCH_), dim3(256), 0, stream>>>(la, cov, 0, 18);
    k_cov_tri<<<dim3(NC_, NCH_), dim3(256), 0, stream>>>(pr, cov, 9, 63);
    k_cov_ab<<<dim3(NC_, NCH_, 3), dim3(256), 0, stream>>>(la, pr, cov);
    k_final<<<dim3(1), dim3(128), 0, stream>>>(cov, (float*)d_out);
}